// Round 10
// baseline (314.845 us; speedup 1.0000x reference)
//
#include <hip/hip_runtime.h>

typedef _Float16 f16x8 __attribute__((ext_vector_type(8)));
typedef _Float16 f16x4 __attribute__((ext_vector_type(4)));
typedef float f32x4 __attribute__((ext_vector_type(4)));
typedef int i32x8 __attribute__((ext_vector_type(8)));
typedef unsigned char u8;

#define DEVI __device__ __forceinline__

constexpr int NROWS = 2048;
constexpr int HEADV = 20002;
constexpr int HEADP = 20480;   // 160*128
constexpr int NCBH  = 160;
constexpr int PSTH  = 160;
constexpr int VT    = 40000;
constexpr int VTP   = 40320;   // 315*128
constexpr int NCBT  = 315;
constexpr int PSTT  = 320;

DEVI void glds16(const void* g, void* l) {
  __builtin_amdgcn_global_load_lds((const __attribute__((address_space(1))) unsigned int*)g,
                                   (__attribute__((address_space(3))) unsigned int*)l,
                                   16, 0, 0);
}

// fp8 storage swizzle: logical 8B-slot sl of row r stored at phys slot sl ^ SIG(r)
#define SIG(r) (((r) >> 1) & 7)

// ---------------- fp8 e4m3fn converters (hand-rolled, RNE) ----------------
DEVI unsigned int to_e4m3(float f) {
  unsigned u = __float_as_uint(f);
  unsigned s = (u >> 24) & 0x80u;
  float a = fabsf(f);
  if (!(a < 448.f)) return s | 0x7E;
  if (a < 0.00097656f) return s;
  int exp = (int)((u >> 23) & 0xFF) - 127;
  int qexp = exp < -6 ? -6 : exp;
  int n = __float2int_rn(a * exp2f((float)(3 - qexp)));
  if (n >= 16) { qexp++; n = 8; }
  return s | (unsigned)(n < 8 ? n : (((qexp + 7) << 3) | (n - 8)));
}

DEVI float fr8(unsigned b) {
  unsigned e = (b >> 3) & 15u, m = b & 7u;
  float v;
  if (e) v = __uint_as_float(((e + 120u) << 23) | (m << 20));
  else   v = (float)m * 0.001953125f;
  return (b & 0x80u) ? -v : v;
}

// ---------------- parallel prep (atomic compaction; list order irrelevant) ----------------
__global__ void prep_par(const int* __restrict__ x, const int* __restrict__ labels,
                         int* cl, int* headcol, int* tailpos, int* pos1, int* pos2,
                         int* L1, int* L2, int* T0, int* T1, int* T2, int* counts)
{
  int n = blockIdx.x * 256 + threadIdx.x;
  int l = labels[n];
  int c = l < 20000 ? 0 : (l < 60000 ? 1 : 2);
  cl[n] = c;
  headcol[n] = c == 0 ? l : (c == 1 ? 20001 : 20000);
  tailpos[n] = c == 1 ? l - 20000 : (c == 2 ? l - 60000 : 0);
  if (c == 1) { int s = atomicAdd(&counts[0], 1); pos1[n] = s; L1[s] = n; }
  else if (c == 2) { int s = atomicAdd(&counts[1], 1); pos2[n] = s; L2[s] = n; }
  int t = x[n];
  int tc = t < 20000 ? 0 : (t < 60000 ? 1 : 2);
  int s = atomicAdd(&counts[2 + tc], 1);
  (tc == 0 ? T0 : tc == 1 ? T1 : T2)[s] = n;
}

// ---------------- fused pack / convert / transpose (+ zero lists/counters) ----------------
constexpr int PB_A = HEADP * 1024 / 8 / 256;          // headw fp8 (swizzled)
constexpr int PB_B = PB_A + VTP * 256 / 8 / 256;      // w1q
constexpr int PB_C = PB_B + VTP * 128 / 8 / 256;      // w2q
constexpr int PB_D = PB_C + 1024;                     // ep0f
constexpr int PB_E = PB_D + 256;                      // ep1f
constexpr int PB_F = PB_E + 64;                       // ep2f
constexpr int PB_G = PB_F + 1024;                     // op0T
constexpr int PB_H = PB_G + 256;                      // op1T
constexpr int PB_I = PB_H + 128;                      // op2T

DEVI void cvt_f16(const float* src, _Float16* dst, int vb, int tid) {
  int g = vb * 256 + tid;
  float4 v = *(const float4*)(src + (size_t)g * 4);
  f16x4 o = {(_Float16)v.x, (_Float16)v.y, (_Float16)v.z, (_Float16)v.w};
  *(f16x4*)(dst + (size_t)g * 4) = o;
}

DEVI void tr32(const float* in, _Float16* out, int C, int bx, int by, int tid) {
  __shared__ float tile[32][33];
  int c0 = bx * 32, r0 = by * 32;
  int tx = tid & 31, ty = tid >> 5;
  for (int i = 0; i < 4; i++) {
    int c = c0 + tx; int r = r0 + ty + i * 8;
    tile[ty + i * 8][tx] = (c < C) ? in[(size_t)r * C + c] : 0.f;
  }
  __syncthreads();
  for (int i = 0; i < 4; i++)
    out[(size_t)(c0 + ty + i * 8) * 1024 + r0 + tx] = (_Float16)tile[tx][ty + i * 8];
}

DEVI unsigned long pack8(const float* v) {
  unsigned long p = 0;
  #pragma unroll
  for (int j = 0; j < 8; j++) p |= (unsigned long)to_e4m3(v[j] * 64.f) << (8 * j);
  return p;
}

__global__ void fused_pack(const float* __restrict__ out_w0, const float* __restrict__ out_b0,
                           const float* __restrict__ cluster_w, const float* __restrict__ cluster_b,
                           const float* __restrict__ out_w1, const float* __restrict__ out_b1,
                           const float* __restrict__ out_w2, const float* __restrict__ out_b2,
                           const float* __restrict__ emb_proj0, const float* __restrict__ emb_proj1,
                           const float* __restrict__ emb_proj2,
                           const float* __restrict__ out_proj0, const float* __restrict__ out_proj1,
                           const float* __restrict__ out_proj2,
                           u8* headw, float* headb,
                           u8* w1q, float* b1p, u8* w2q, float* b2p,
                           _Float16* ep0f, _Float16* ep1f, _Float16* ep2f,
                           _Float16* op0T, _Float16* op1T, _Float16* op2T,
                           int* lists, int* counts)
{
  int bid = blockIdx.x, tid = threadIdx.x;
  int zi = bid * 256 + tid;
  if (zi < 5 * 2048) lists[zi] = 0;
  if (bid == 41 && tid < 8) counts[tid] = 0;
  if (bid < PB_A) {
    int g = bid * 256 + tid;
    int r = g >> 7, sl = g & 127;
    float v[8] = {};
    if (r < 20000) {
      *(float4*)v = *(const float4*)(out_w0 + (size_t)r * 1024 + sl * 8);
      *(float4*)(v + 4) = *(const float4*)(out_w0 + (size_t)r * 1024 + sl * 8 + 4);
    } else if (r < 20002) {
      *(float4*)v = *(const float4*)(cluster_w + (size_t)(r - 20000) * 1024 + sl * 8);
      *(float4*)(v + 4) = *(const float4*)(cluster_w + (size_t)(r - 20000) * 1024 + sl * 8 + 4);
    }
    *(unsigned long*)(headw + (size_t)r * 1024 + ((sl ^ SIG(r)) << 3)) = pack8(v);
    if (g < HEADP) headb[g] = g < 20000 ? out_b0[g] : (g < HEADV ? cluster_b[g - 20000] : -1e30f);
  } else if (bid < PB_B) {
    int g = (bid - PB_A) * 256 + tid;
    int r = g >> 5, sl = g & 31;
    float v[8] = {};
    if (r < VT) {
      *(float4*)v = *(const float4*)(out_w1 + (size_t)r * 256 + sl * 8);
      *(float4*)(v + 4) = *(const float4*)(out_w1 + (size_t)r * 256 + sl * 8 + 4);
    }
    *(unsigned long*)(w1q + (size_t)r * 256 + ((sl ^ SIG(r)) << 3)) = pack8(v);
    if (g < VTP) b1p[g] = g < VT ? out_b1[g] : -1e30f;
  } else if (bid < PB_C) {
    int g = (bid - PB_B) * 256 + tid;
    int r = g >> 4, sl = g & 15;
    float v[8] = {};
    if (r < VT && sl < 8) {
      *(float4*)v = *(const float4*)(out_w2 + (size_t)r * 64 + sl * 8);
      *(float4*)(v + 4) = *(const float4*)(out_w2 + (size_t)r * 64 + sl * 8 + 4);
    }
    *(unsigned long*)(w2q + (size_t)r * 128 + ((sl ^ SIG(r)) << 3)) = pack8(v);
    if (g < VTP) b2p[g] = g < VT ? out_b2[g] : -1e30f;
  } else if (bid < PB_D) { cvt_f16(emb_proj0, ep0f, bid - PB_C, tid); }
  else if (bid < PB_E) { cvt_f16(emb_proj1, ep1f, bid - PB_D, tid); }
  else if (bid < PB_F) { cvt_f16(emb_proj2, ep2f, bid - PB_E, tid); }
  else if (bid < PB_G) { int l = bid - PB_F; tr32(out_proj0, op0T, 1024, l & 31, l >> 5, tid); }
  else if (bid < PB_H) { int l = bid - PB_G; tr32(out_proj1, op1T, 256, l & 7, l >> 3, tid); }
  else                 { int l = bid - PB_H; tr32(out_proj2, op2T, 64, l & 3, l >> 2, tid); }
}

// ---------------- fused gather ----------------
DEVI void gat(const float* emb, const int* x, const int* list, _Float16* dst,
              int tbase, int vmax, int log2E, int vb, int tid) {
  int g = vb * 256 + tid;
  int r = g >> (log2E - 2);
  int e4 = (g & ((1 << (log2E - 2)) - 1)) << 2;
  int n = list[r];
  int tl = x[n] - tbase;
  tl = tl < 0 ? 0 : (tl >= vmax ? vmax - 1 : tl);
  float4 v = *(const float4*)(emb + ((size_t)tl << log2E) + e4);
  f16x4 o = {(_Float16)(v.x * 32.f), (_Float16)(v.y * 32.f),
             (_Float16)(v.z * 32.f), (_Float16)(v.w * 32.f)};
  *(f16x4*)(dst + ((size_t)r << log2E) + e4) = o;
}

__global__ void fused_gather(const float* __restrict__ emb_w0, const float* __restrict__ emb_w1,
                             const float* __restrict__ emb_w2, const int* __restrict__ x,
                             const int* __restrict__ T0, const int* __restrict__ T1,
                             const int* __restrict__ T2,
                             _Float16* E0, _Float16* E1, _Float16* E2)
{
  int bid = blockIdx.x, tid = threadIdx.x;
  if (bid < 2048)      gat(emb_w0, x, T0, E0, 0, 20000, 10, bid, tid);
  else if (bid < 2560) gat(emb_w1, x, T1, E1, 20000, 40000, 8, bid - 2048, tid);
  else                 gat(emb_w2, x, T2, E2, 60000, 40000, 6, bid - 2560, tid);
}

// ---------------- 128-tile f16 GEMM body + 3-segment wrapper ----------------
struct Seg128 {
  const _Float16* A; int lda;
  const _Float16* Wm; int ldw;
  _Float16* C; int ldc; int Nvalid;
  u8* Cq; int ldq;
  const int* amap; const int* cmap; const int* cnt;
  int K; int nblk;
};

DEVI void gemm128_body(const Seg128& s, int rb, int cb) {
  int valid = s.cnt ? *s.cnt : NROWS;
  if (rb * 128 >= valid) return;
  __shared__ __attribute__((aligned(16))) _Float16 As[128 * 32];
  __shared__ __attribute__((aligned(16))) _Float16 Ws[128 * 32];
  int tid = threadIdx.x;
  int lane = tid & 63, wid = tid >> 6;
  int wr = wid >> 1, wc = wid & 1;
  int sr = wid * 32 + (lane >> 2);
  int arow0 = rb * 128 + sr, arow1 = arow0 + 16;
  if (s.amap) { arow0 = s.amap[arow0]; arow1 = s.amap[arow1]; }
  int ko = (lane & 3) * 8;
  const _Float16* ag0 = s.A + (size_t)arow0 * s.lda + ko;
  const _Float16* ag1 = s.A + (size_t)arow1 * s.lda + ko;
  const _Float16* wg0 = s.Wm + (size_t)(cb * 128 + sr) * s.ldw + ko;
  const _Float16* wg1 = wg0 + (size_t)16 * s.ldw;
  _Float16* as0 = As + (wid * 32) * 32;
  _Float16* as1 = as0 + 16 * 32;
  _Float16* ws0 = Ws + (wid * 32) * 32;
  _Float16* ws1 = ws0 + 16 * 32;
  f32x4 acc[4][4] = {};
  int lr = lane & 15, lk = (lane >> 4) * 8;
  const int nk = s.K >> 5;
  for (int kt = 0; kt < nk; ++kt) {
    int kofs = kt * 32;
    glds16(ag0 + kofs, as0);
    glds16(ag1 + kofs, as1);
    glds16(wg0 + kofs, ws0);
    glds16(wg1 + kofs, ws1);
    __syncthreads();
    f16x8 af[4], bf[4];
    #pragma unroll
    for (int mi = 0; mi < 4; mi++)
      af[mi] = *(const f16x8*)(As + (wr * 64 + mi * 16 + lr) * 32 + lk);
    #pragma unroll
    for (int ni = 0; ni < 4; ni++)
      bf[ni] = *(const f16x8*)(Ws + (wc * 64 + ni * 16 + lr) * 32 + lk);
    #pragma unroll
    for (int mi = 0; mi < 4; mi++)
      #pragma unroll
      for (int ni = 0; ni < 4; ni++)
        acc[mi][ni] = __builtin_amdgcn_mfma_f32_16x16x32_f16(af[mi], bf[ni], acc[mi][ni], 0, 0, 0);
    __syncthreads();
  }
  #pragma unroll
  for (int mi = 0; mi < 4; mi++) {
    #pragma unroll
    for (int j = 0; j < 4; j++) {
      int rl = wr * 64 + mi * 16 + (lane >> 4) * 4 + j;
      int rg = rb * 128 + rl;
      if (rg >= valid) continue;
      int orow = s.cmap ? s.cmap[rg] : rg;
      #pragma unroll
      for (int ni = 0; ni < 4; ni++) {
        int col = cb * 128 + wc * 64 + ni * 16 + (lane & 15);
        if (col < s.Nvalid) {
          float v = acc[mi][ni][j];
          s.C[(size_t)orow * s.ldc + col] = (_Float16)v;
          if (s.Cq) {
            int sl = col >> 3;
            s.Cq[(size_t)orow * s.ldq + (((sl ^ SIG(orow)) << 3) | (col & 7))] = (u8)to_e4m3(v * 8.f);
          }
        }
      }
    }
  }
}

__global__ __launch_bounds__(256)
void gemm128_multi(Seg128 s0, Seg128 s1, Seg128 s2) {
  int b = blockIdx.x;
  if (b < s0.nblk)                    { gemm128_body(s0, b & 15, b >> 4); }
  else if (b < s0.nblk + s1.nblk)     { b -= s0.nblk; gemm128_body(s1, b & 15, b >> 4); }
  else                                { b -= s0.nblk + s1.nblk; gemm128_body(s2, b & 15, b >> 4); }
}

// ------- MX-fp8 128x128 GEMM + online-LSE (m148 blueprint: BK=128, 4 waves, 3 blk/CU) -------
struct SegL {
  const u8* A; const u8* W; const float* bias; const int* cnt;
  float* pm; float* ps; int pstride; int K; int nrb; int nblk;
};

__global__ __launch_bounds__(256)
void gemm_lse8_multi(SegL s0, SegL s1, SegL s2)
{
  __shared__ __attribute__((aligned(16))) u8 As[16384];   // 128 rows x 128B
  __shared__ __attribute__((aligned(16))) u8 Ws[16384];

  int b = blockIdx.x;
  SegL s;
  if (b < s0.nblk) s = s0;
  else if (b < s0.nblk + s1.nblk) { s = s1; b -= s0.nblk; }
  else { s = s2; b -= s0.nblk + s1.nblk; }

  int q = s.nblk >> 3;                       // nblk % 8 == 0
  int w = (b & 7) * q + (b >> 3);            // XCD-contiguous cb panels
  int rb = w % s.nrb, cb = w / s.nrb;
  int valid = s.cnt ? *s.cnt : NROWS;
  if (rb * 128 >= valid) return;

  const int K = s.K;
  int tid = threadIdx.x;
  int lane = tid & 63, wid = tid >> 6;
  int wr = wid >> 1, wc = wid & 1;
  int lr = lane & 15, g = lane >> 4;

  // staging: 1024 16B-chunks per matrix, 4 per thread; global pre-swizzled (pure memcpy)
  const u8* aS[4]; const u8* bS[4]; int dL[4];
  #pragma unroll
  for (int i = 0; i < 4; ++i) {
    int c = tid + i * 256;
    int r = c >> 3, j = c & 7;
    aS[i] = s.A + (size_t)(rb * 128 + r) * K + j * 16;
    bS[i] = s.W + (size_t)((size_t)cb * 128 + r) * K + j * 16;
    dL[i] = c * 16;
  }

  // fragment reads: row base + 4x ds_read_b64 at ((slot^SIG)*8); slots g*4..g*4+3
  int sig = (lr >> 1) & 7;
  int o0 = ((g * 4 + 0) ^ sig) << 3;
  int o1 = ((g * 4 + 1) ^ sig) << 3;
  int o2 = ((g * 4 + 2) ^ sig) << 3;
  int o3 = ((g * 4 + 3) ^ sig) << 3;
  int arow = (wr * 64 + lr) * 128;           // + mi*2048
  int brow = (wc * 64 + lr) * 128;           // + ni*2048

  f32x4 acc[4][4] = {};
  const int nk = K >> 7;                     // BK = 128 bytes; nk >= 1

  union UV { i32x8 v; long l[4]; };
  for (int kt = 0; kt < nk; ++kt) {
    int k0 = kt * 128;
    #pragma unroll
    for (int i = 0; i < 4; ++i) glds16(aS[i] + k0, As + dL[i]);
    #pragma unroll
    for (int i = 0; i < 4; ++i) glds16(bS[i] + k0, Ws + dL[i]);
    __syncthreads();            // compiler drains vmcnt before barrier
    i32x8 bq[4];
    #pragma unroll
    for (int ni = 0; ni < 4; ++ni) {
      UV bv;
      const u8* bp = Ws + brow + ni * 2048;
      bv.l[0] = *(const long*)(bp + o0);
      bv.l[1] = *(const long*)(bp + o1);
      bv.l[2] = *(const long*)(bp + o2);
      bv.l[3] = *(const long*)(bp + o3);
      bq[ni] = bv.v;
    }
    #pragma unroll
    for (int mi = 0; mi < 4; ++mi) {
      UV av;
      const u8* ap = As + arow + mi * 2048;
      av.l[0] = *(const long*)(ap + o0);
      av.l[1] = *(const long*)(ap + o1);
      av.l[2] = *(const long*)(ap + o2);
      av.l[3] = *(const long*)(ap + o3);
      #pragma unroll
      for (int ni = 0; ni < 4; ++ni)
        acc[mi][ni] = __builtin_amdgcn_mfma_scale_f32_16x16x128_f8f6f4(
                        av.v, bq[ni], acc[mi][ni], 0, 0, 0, 127, 0, 127);
    }
    __syncthreads();
  }

  // ---- epilogue: unscale 1/512 + bias, per-row (max,sumexp) over 128 cols ----
  float* lm = (float*)As;                    // [2 wc][128 rows]
  float* lsm = lm + 256;
  float bv4[4];
  #pragma unroll
  for (int ni = 0; ni < 4; ++ni) bv4[ni] = s.bias[cb * 128 + wc * 64 + ni * 16 + lr];
  constexpr float INV = 1.f / 512.f;
  #pragma unroll
  for (int mi = 0; mi < 4; ++mi) {
    #pragma unroll
    for (int j = 0; j < 4; ++j) {
      float v0 = acc[mi][0][j] * INV + bv4[0];
      float v1 = acc[mi][1][j] * INV + bv4[1];
      float v2 = acc[mi][2][j] * INV + bv4[2];
      float v3 = acc[mi][3][j] * INV + bv4[3];
      float m = fmaxf(fmaxf(v0, v1), fmaxf(v2, v3));
      #pragma unroll
      for (int d = 1; d < 16; d <<= 1) m = fmaxf(m, __shfl_xor(m, d));
      float sm = __expf(v0 - m) + __expf(v1 - m) + __expf(v2 - m) + __expf(v3 - m);
      #pragma unroll
      for (int d = 1; d < 16; d <<= 1) sm += __shfl_xor(sm, d);
      if (lr == 0) {
        int row = wr * 64 + mi * 16 + g * 4 + j;
        lm[wc * 128 + row] = m; lsm[wc * 128 + row] = sm;
      }
    }
  }
  __syncthreads();
  if (tid < 128) {
    float m0 = lm[tid], m1 = lm[128 + tid];
    float M = fmaxf(m0, m1);
    float S = lsm[tid] * __expf(m0 - M) + lsm[128 + tid] * __expf(m1 - M);
    int gr = rb * 128 + tid;
    s.pm[(size_t)gr * s.pstride + cb] = M;
    s.ps[(size_t)gr * s.pstride + cb] = S;
  }
}

// ---------------- finish: target logits + LSE reduce + NLL ----------------
DEVI float lsew(const float* m, const float* s, int nb, int lane) {
  float M = -3e38f;
  for (int i = lane; i < nb; i += 64) M = fmaxf(M, m[i]);
  #pragma unroll
  for (int d = 1; d < 64; d <<= 1) M = fmaxf(M, __shfl_xor(M, d));
  float S = 0.f;
  for (int i = lane; i < nb; i += 64) S += s[i] * __expf(m[i] - M);
  #pragma unroll
  for (int d = 1; d < 64; d <<= 1) S += __shfl_xor(S, d);
  return M + __logf(S);
}

__global__ void finish_kernel(const _Float16* __restrict__ ph0, const u8* __restrict__ headw,
                              const float* __restrict__ headb,
                              const _Float16* __restrict__ ph1c, const u8* __restrict__ w1q,
                              const float* __restrict__ b1p,
                              const _Float16* __restrict__ ph2c, const u8* __restrict__ w2q,
                              const float* __restrict__ b2p,
                              const int* __restrict__ headcol, const int* __restrict__ tailpos,
                              const int* __restrict__ pos1, const int* __restrict__ pos2,
                              const int* __restrict__ cl,
                              const float* __restrict__ pmh, const float* __restrict__ psh,
                              const float* __restrict__ pm1, const float* __restrict__ ps1,
                              const float* __restrict__ pm2, const float* __restrict__ ps2,
                              float* __restrict__ out)
{
  int n = blockIdx.x;
  int tid = threadIdx.x, lane = tid & 63, wid = tid >> 6;
  __shared__ float sh[6];
  int c = cl[n];
  constexpr float IW = 1.f / 64.f;
  if (wid == 0) {
    int hc = headcol[n];
    const f16x8* a = (const f16x8*)(ph0 + (size_t)n * 1024 + lane * 16);
    float s = 0.f;
    #pragma unroll
    for (int u = 0; u < 2; u++) {
      int sl = lane * 2 + u;
      unsigned long wq = *(const unsigned long*)(headw + (size_t)hc * 1024 + (((sl ^ SIG(hc)) << 3)));
      f16x8 av = a[u];
      #pragma unroll
      for (int j = 0; j < 8; j++) s += (float)av[j] * fr8((unsigned)(wq >> (8 * j)) & 0xFFu);
    }
    #pragma unroll
    for (int d = 1; d < 64; d <<= 1) s += __shfl_xor(s, d);
    if (lane == 0) sh[0] = s * IW + headb[hc];
  } else if (wid == 1 && c == 1) {
    int p = pos1[n], t = tailpos[n];
    f16x4 av = *(const f16x4*)(ph1c + (size_t)p * 256 + lane * 4);
    int sl = lane >> 1;
    const u8* ww = w1q + (size_t)t * 256 + ((sl ^ SIG(t)) << 3) + (lane & 1) * 4;
    float s = (float)av[0] * fr8(ww[0]) + (float)av[1] * fr8(ww[1])
            + (float)av[2] * fr8(ww[2]) + (float)av[3] * fr8(ww[3]);
    #pragma unroll
    for (int d = 1; d < 64; d <<= 1) s += __shfl_xor(s, d);
    float l = lsew(pm1 + (size_t)p * PSTT, ps1 + (size_t)p * PSTT, NCBT, lane);
    if (lane == 0) { sh[1] = s * IW + b1p[t]; sh[4] = l; }
  } else if (wid == 2 && c == 2) {
    int p = pos2[n], t = tailpos[n];
    const _Float16* a = ph2c + (size_t)p * 128 + lane * 2;
    int sl = lane >> 2;
    const u8* ww = w2q + (size_t)t * 128 + ((sl ^ SIG(t)) << 3) + (lane & 3) * 2;
    float s = (float)a[0] * fr8(ww[0]) + (float)a[1] * fr8(ww[1]);
    #pragma unroll
    for (int d = 1; d < 64; d <<= 1) s += __shfl_xor(s, d);
    float l = lsew(pm2 + (size_t)p * PSTT, ps2 + (size_t)p * PSTT, NCBT, lane);
    if (lane == 0) { sh[2] = s * IW + b2p[t]; sh[5] = l; }
  } else if (wid == 3) {
    float l = lsew(pmh + (size_t)n * PSTH, psh + (size_t)n * PSTH, NCBH, lane);
    if (lane == 0) sh[3] = l;
  }
  __syncthreads();
  if (tid == 0) {
    float nll = sh[3] - sh[0];
    if (c == 1)      nll += sh[4] - sh[1];
    else if (c == 2) nll += sh[5] - sh[2];
    out[n] = nll;
  }
}

// ---------------- driver ----------------
extern "C" void kernel_launch(void* const* d_in, const int* in_sizes, int n_in,
                              void* d_out, int out_size, void* d_ws, size_t ws_size,
                              hipStream_t stream)
{
  const int*   x         = (const int*)d_in[0];
  const int*   labels    = (const int*)d_in[1];
  const float* emb_w0    = (const float*)d_in[2];
  const float* emb_w1    = (const float*)d_in[3];
  const float* emb_w2    = (const float*)d_in[4];
  const float* emb_proj0 = (const float*)d_in[5];
  const float* emb_proj1 = (const float*)d_in[6];
  const float* emb_proj2 = (const float*)d_in[7];
  const float* out_w0    = (const float*)d_in[8];
  const float* out_b0    = (const float*)d_in[9];
  const float* out_w1    = (const float*)d_in[10];
  const float* out_b1    = (const float*)d_in[11];
  const float* out_w2    = (const float*)d_in[12];
  const float* out_b2    = (const float*)d_in[13];
  const float* out_proj0 = (const float*)d_in[14];
  const float* out_proj1 = (const float*)d_in[15];
  const float* out_proj2 = (const float*)d_in[16];
  const float* cluster_w = (const float*)d_in[17];
  const float* cluster_b = (const float*)d_in[18];
  float* out = (float*)d_out;

  char* ws = (char*)d_ws;
  size_t off = 0;
  auto alloc = [&](size_t bytes) -> void* {
    void* p = ws + off;
    off = (off + bytes + 255) & ~(size_t)255;
    return p;
  };
  u8*    headw = (u8*)alloc((size_t)HEADP * 1024);
  float* headb = (float*)alloc((size_t)HEADP * 4);
  u8*    w1q   = (u8*)alloc((size_t)VTP * 256);
  float* b1p   = (float*)alloc((size_t)VTP * 4);
  u8*    w2q   = (u8*)alloc((size_t)VTP * 128);
  float* b2p   = (float*)alloc((size_t)VTP * 4);
  _Float16* ep0f = (_Float16*)alloc((size_t)1024 * 1024 * 2);
  _Float16* ep1f = (_Float16*)alloc((size_t)1024 * 256 * 2);
  _Float16* ep2f = (_Float16*)alloc((size_t)1024 * 64 * 2);
  _Float16* op0T = (_Float16*)alloc((size_t)1024 * 1024 * 2);
  _Float16* op1T = (_Float16*)alloc((size_t)256 * 1024 * 2);
  _Float16* op2T = (_Float16*)alloc((size_t)128 * 1024 * 2);
  _Float16* E0   = (_Float16*)alloc((size_t)NROWS * 1024 * 2);
  _Float16* E1   = (_Float16*)alloc((size_t)NROWS * 256 * 2);
  _Float16* E2   = (_Float16*)alloc((size_t)NROWS * 64 * 2);
  _Float16* hid  = (_Float16*)alloc((size_t)NROWS * 1024 * 2);
  _Float16* ph0  = (_Float16*)alloc((size_t)NROWS * 1024 * 2);
  u8*       ph0q = (u8*)alloc((size_t)NROWS * 1024);
  _Float16* ph1c = (_Float16*)alloc((size_t)NROWS * 256 * 2);
  u8*       ph1q = (u8*)alloc((size_t)NROWS * 256);
  _Float16* ph2c = (_Float16*)alloc((size_t)NROWS * 128 * 2);
  u8*       ph2q = (u8*)alloc((size_t)NROWS * 128);
  float* pmh = (float*)alloc((size_t)NROWS * PSTH * 4);
  float* psh = (float*)alloc((size_t)NROWS * PSTH * 4);
  float* pm1 = (float*)alloc((size_t)NROWS * PSTT * 4);
  float* ps1 = (float*)alloc((size_t)NROWS * PSTT * 4);
  float* pm2 = (float*)alloc((size_t)NROWS * PSTT * 4);
  float* ps2 = (float*)alloc((size_t)NROWS * PSTT * 4);
  int* lists = (int*)alloc(5 * NROWS * 4);
  int* L1 = lists;
  int* L2 = lists + 2048;
  int* T0 = lists + 4096;
  int* T1 = lists + 6144;
  int* T2 = lists + 8192;
  int* counts  = (int*)alloc(16 * 4);
  int* cl      = (int*)alloc(NROWS * 4);
  int* headcol = (int*)alloc(NROWS * 4);
  int* tailpos = (int*)alloc(NROWS * 4);
  int* pos1    = (int*)alloc(NROWS * 4);
  int* pos2    = (int*)alloc(NROWS * 4);
  (void)ws_size; (void)in_sizes; (void)n_in; (void)out_size;

  fused_pack<<<PB_I, 256, 0, stream>>>(out_w0, out_b0, cluster_w, cluster_b,
                                       out_w1, out_b1, out_w2, out_b2,
                                       emb_proj0, emb_proj1, emb_proj2,
                                       out_proj0, out_proj1, out_proj2,
                                       headw, headb, w1q, b1p, w2q, b2p,
                                       ep0f, ep1f, ep2f, op0T, op1T, op2T,
                                       lists, counts);

  prep_par<<<8, 256, 0, stream>>>(x, labels, cl, headcol, tailpos, pos1, pos2,
                                  L1, L2, T0, T1, T2, counts);

  fused_gather<<<2688, 256, 0, stream>>>(emb_w0, emb_w1, emb_w2, x, T0, T1, T2, E0, E1, E2);

  // hidden per token cluster (scatter via T-lists): 3 segments, one launch
  Seg128 h0 = {E0, 1024, ep0f, 1024, hid, 1024, 1024, nullptr, 0, nullptr, T0, counts + 2, 1024, 128};
  Seg128 h1 = {E1, 256,  ep1f, 256,  hid, 1024, 1024, nullptr, 0, nullptr, T1, counts + 3, 256,  128};
  Seg128 h2 = {E2, 64,   ep2f, 64,   hid, 1024, 1024, nullptr, 0, nullptr, T2, counts + 4, 64,   128};
  gemm128_multi<<<384, 256, 0, stream>>>(h0, h1, h2);

  // projections (dual-write f16 + swizzled fp8 x8): 3 segments, one launch
  Seg128 p0 = {hid, 1024, op0T, 1024, ph0,  1024, 1024, ph0q, 1024, nullptr, nullptr, nullptr,   1024, 128};
  Seg128 p1 = {hid, 1024, op1T, 1024, ph1c, 256,  256,  ph1q, 256,  L1,      nullptr, counts + 0, 1024, 32};
  Seg128 p2 = {hid, 1024, op2T, 1024, ph2c, 128,  128,  ph2q, 128,  L2,      nullptr, counts + 1, 1024, 16};
  gemm128_multi<<<176, 256, 0, stream>>>(p0, p1, p2);

  // MX-fp8 logits + online-LSE partials: head + both tails in ONE launch (128x128, BK=128)
  SegL l0 = {ph0q, headw, headb, nullptr,    pmh, psh, PSTH, 1024, 16, 16 * NCBH};
  SegL l1 = {ph1q, w1q,   b1p,   counts + 0, pm1, ps1, PSTT, 256,  8,  8 * NCBT};
  SegL l2 = {ph2q, w2q,   b2p,   counts + 1, pm2, ps2, PSTT, 128,  8,  8 * NCBT};
  gemm_lse8_multi<<<16 * NCBH + 16 * NCBT, 256, 0, stream>>>(l0, l1, l2);

  finish_kernel<<<NROWS, 256, 0, stream>>>(ph0, headw, headb, ph1c, w1q, b1p,
                                           ph2c, w2q, b2p, headcol, tailpos, pos1, pos2, cl,
                                           pmh, psh, pm1, ps1, pm2, ps2, out);
}

// Round 11
// 255.356 us; speedup vs baseline: 1.2330x; 1.2330x over previous
//
#include <hip/hip_runtime.h>

typedef _Float16 f16x8 __attribute__((ext_vector_type(8)));
typedef _Float16 f16x4 __attribute__((ext_vector_type(4)));
typedef float f32x4 __attribute__((ext_vector_type(4)));
typedef int i32x4 __attribute__((ext_vector_type(4)));
typedef int i32x8 __attribute__((ext_vector_type(8)));
typedef unsigned char u8;

#define DEVI __device__ __forceinline__

constexpr int NROWS = 2048;
constexpr int HEADV = 20002;
constexpr int HEADP = 20480;   // 160*128
constexpr int NCBH  = 160;
constexpr int PSTH  = 160;
constexpr int VT    = 40000;
constexpr int VTP   = 40320;   // 315*128
constexpr int NCBT  = 315;
constexpr int PSTT  = 320;

DEVI void glds16(const void* g, void* l) {
  __builtin_amdgcn_global_load_lds((const __attribute__((address_space(1))) unsigned int*)g,
                                   (__attribute__((address_space(3))) unsigned int*)l,
                                   16, 0, 0);
}

// fp8 storage swizzle, 16B granularity within each 128B K-group:
// logical byte b of row r lives at phys swzb(b,r). Involution; staging is linear memcpy.
#define SIG(r) (((r) >> 1) & 7)
DEVI int swzb(int b, int r) {
  return (b & ~127) | ((((b >> 4) & 7) ^ SIG(r)) << 4) | (b & 15);
}

// ---------------- fp8 e4m3fn converters (hand-rolled, RNE) ----------------
DEVI unsigned int to_e4m3(float f) {
  unsigned u = __float_as_uint(f);
  unsigned s = (u >> 24) & 0x80u;
  float a = fabsf(f);
  if (!(a < 448.f)) return s | 0x7E;
  if (a < 0.00097656f) return s;
  int exp = (int)((u >> 23) & 0xFF) - 127;
  int qexp = exp < -6 ? -6 : exp;
  int n = __float2int_rn(a * exp2f((float)(3 - qexp)));
  if (n >= 16) { qexp++; n = 8; }
  return s | (unsigned)(n < 8 ? n : (((qexp + 7) << 3) | (n - 8)));
}

DEVI float fr8(unsigned b) {
  unsigned e = (b >> 3) & 15u, m = b & 7u;
  float v;
  if (e) v = __uint_as_float(((e + 120u) << 23) | (m << 20));
  else   v = (float)m * 0.001953125f;
  return (b & 0x80u) ? -v : v;
}

// ---------------- parallel prep (atomic compaction; list order irrelevant) ----------------
__global__ void prep_par(const int* __restrict__ x, const int* __restrict__ labels,
                         int* cl, int* headcol, int* tailpos, int* pos1, int* pos2,
                         int* L1, int* L2, int* T0, int* T1, int* T2, int* counts)
{
  int n = blockIdx.x * 256 + threadIdx.x;
  int l = labels[n];
  int c = l < 20000 ? 0 : (l < 60000 ? 1 : 2);
  cl[n] = c;
  headcol[n] = c == 0 ? l : (c == 1 ? 20001 : 20000);
  tailpos[n] = c == 1 ? l - 20000 : (c == 2 ? l - 60000 : 0);
  if (c == 1) { int s = atomicAdd(&counts[0], 1); pos1[n] = s; L1[s] = n; }
  else if (c == 2) { int s = atomicAdd(&counts[1], 1); pos2[n] = s; L2[s] = n; }
  int t = x[n];
  int tc = t < 20000 ? 0 : (t < 60000 ? 1 : 2);
  int s = atomicAdd(&counts[2 + tc], 1);
  (tc == 0 ? T0 : tc == 1 ? T1 : T2)[s] = n;
}

// ---------------- fused pack / convert / transpose (+ zero lists/counters) ----------------
constexpr int PB_A = HEADP * 1024 / 8 / 256;          // headw fp8 (swizzled)
constexpr int PB_B = PB_A + VTP * 256 / 8 / 256;      // w1q
constexpr int PB_C = PB_B + VTP * 128 / 8 / 256;      // w2q
constexpr int PB_D = PB_C + 1024;                     // ep0f
constexpr int PB_E = PB_D + 256;                      // ep1f
constexpr int PB_F = PB_E + 64;                       // ep2f
constexpr int PB_G = PB_F + 1024;                     // op0T
constexpr int PB_H = PB_G + 256;                      // op1T
constexpr int PB_I = PB_H + 128;                      // op2T

DEVI void cvt_f16(const float* src, _Float16* dst, int vb, int tid) {
  int g = vb * 256 + tid;
  float4 v = *(const float4*)(src + (size_t)g * 4);
  f16x4 o = {(_Float16)v.x, (_Float16)v.y, (_Float16)v.z, (_Float16)v.w};
  *(f16x4*)(dst + (size_t)g * 4) = o;
}

DEVI void tr32(const float* in, _Float16* out, int C, int bx, int by, int tid) {
  __shared__ float tile[32][33];
  int c0 = bx * 32, r0 = by * 32;
  int tx = tid & 31, ty = tid >> 5;
  for (int i = 0; i < 4; i++) {
    int c = c0 + tx; int r = r0 + ty + i * 8;
    tile[ty + i * 8][tx] = (c < C) ? in[(size_t)r * C + c] : 0.f;
  }
  __syncthreads();
  for (int i = 0; i < 4; i++)
    out[(size_t)(c0 + ty + i * 8) * 1024 + r0 + tx] = (_Float16)tile[tx][ty + i * 8];
}

DEVI unsigned long pack8(const float* v) {
  unsigned long p = 0;
  #pragma unroll
  for (int j = 0; j < 8; j++) p |= (unsigned long)to_e4m3(v[j] * 64.f) << (8 * j);
  return p;
}

__global__ void fused_pack(const float* __restrict__ out_w0, const float* __restrict__ out_b0,
                           const float* __restrict__ cluster_w, const float* __restrict__ cluster_b,
                           const float* __restrict__ out_w1, const float* __restrict__ out_b1,
                           const float* __restrict__ out_w2, const float* __restrict__ out_b2,
                           const float* __restrict__ emb_proj0, const float* __restrict__ emb_proj1,
                           const float* __restrict__ emb_proj2,
                           const float* __restrict__ out_proj0, const float* __restrict__ out_proj1,
                           const float* __restrict__ out_proj2,
                           u8* headw, float* headb,
                           u8* w1q, float* b1p, u8* w2q, float* b2p,
                           _Float16* ep0f, _Float16* ep1f, _Float16* ep2f,
                           _Float16* op0T, _Float16* op1T, _Float16* op2T,
                           int* lists, int* counts)
{
  int bid = blockIdx.x, tid = threadIdx.x;
  int zi = bid * 256 + tid;
  if (zi < 5 * 2048) lists[zi] = 0;
  if (bid == 41 && tid < 8) counts[tid] = 0;
  if (bid < PB_A) {
    int g = bid * 256 + tid;
    int r = g >> 7, sl = g & 127;
    float v[8] = {};
    if (r < 20000) {
      *(float4*)v = *(const float4*)(out_w0 + (size_t)r * 1024 + sl * 8);
      *(float4*)(v + 4) = *(const float4*)(out_w0 + (size_t)r * 1024 + sl * 8 + 4);
    } else if (r < 20002) {
      *(float4*)v = *(const float4*)(cluster_w + (size_t)(r - 20000) * 1024 + sl * 8);
      *(float4*)(v + 4) = *(const float4*)(cluster_w + (size_t)(r - 20000) * 1024 + sl * 8 + 4);
    }
    *(unsigned long*)(headw + (size_t)r * 1024 + swzb(sl * 8, r)) = pack8(v);
    if (g < HEADP) headb[g] = g < 20000 ? out_b0[g] : (g < HEADV ? cluster_b[g - 20000] : -1e30f);
  } else if (bid < PB_B) {
    int g = (bid - PB_A) * 256 + tid;
    int r = g >> 5, sl = g & 31;
    float v[8] = {};
    if (r < VT) {
      *(float4*)v = *(const float4*)(out_w1 + (size_t)r * 256 + sl * 8);
      *(float4*)(v + 4) = *(const float4*)(out_w1 + (size_t)r * 256 + sl * 8 + 4);
    }
    *(unsigned long*)(w1q + (size_t)r * 256 + swzb(sl * 8, r)) = pack8(v);
    if (g < VTP) b1p[g] = g < VT ? out_b1[g] : -1e30f;
  } else if (bid < PB_C) {
    int g = (bid - PB_B) * 256 + tid;
    int r = g >> 4, sl = g & 15;
    float v[8] = {};
    if (r < VT && sl < 8) {
      *(float4*)v = *(const float4*)(out_w2 + (size_t)r * 64 + sl * 8);
      *(float4*)(v + 4) = *(const float4*)(out_w2 + (size_t)r * 64 + sl * 8 + 4);
    }
    *(unsigned long*)(w2q + (size_t)r * 128 + swzb(sl * 8, r)) = pack8(v);
    if (g < VTP) b2p[g] = g < VT ? out_b2[g] : -1e30f;
  } else if (bid < PB_D) { cvt_f16(emb_proj0, ep0f, bid - PB_C, tid); }
  else if (bid < PB_E) { cvt_f16(emb_proj1, ep1f, bid - PB_D, tid); }
  else if (bid < PB_F) { cvt_f16(emb_proj2, ep2f, bid - PB_E, tid); }
  else if (bid < PB_G) { int l = bid - PB_F; tr32(out_proj0, op0T, 1024, l & 31, l >> 5, tid); }
  else if (bid < PB_H) { int l = bid - PB_G; tr32(out_proj1, op1T, 256, l & 7, l >> 3, tid); }
  else                 { int l = bid - PB_H; tr32(out_proj2, op2T, 64, l & 3, l >> 2, tid); }
}

// ---------------- fused gather ----------------
DEVI void gat(const float* emb, const int* x, const int* list, _Float16* dst,
              int tbase, int vmax, int log2E, int vb, int tid) {
  int g = vb * 256 + tid;
  int r = g >> (log2E - 2);
  int e4 = (g & ((1 << (log2E - 2)) - 1)) << 2;
  int n = list[r];
  int tl = x[n] - tbase;
  tl = tl < 0 ? 0 : (tl >= vmax ? vmax - 1 : tl);
  float4 v = *(const float4*)(emb + ((size_t)tl << log2E) + e4);
  f16x4 o = {(_Float16)(v.x * 32.f), (_Float16)(v.y * 32.f),
             (_Float16)(v.z * 32.f), (_Float16)(v.w * 32.f)};
  *(f16x4*)(dst + ((size_t)r << log2E) + e4) = o;
}

__global__ void fused_gather(const float* __restrict__ emb_w0, const float* __restrict__ emb_w1,
                             const float* __restrict__ emb_w2, const int* __restrict__ x,
                             const int* __restrict__ T0, const int* __restrict__ T1,
                             const int* __restrict__ T2,
                             _Float16* E0, _Float16* E1, _Float16* E2)
{
  int bid = blockIdx.x, tid = threadIdx.x;
  if (bid < 2048)      gat(emb_w0, x, T0, E0, 0, 20000, 10, bid, tid);
  else if (bid < 2560) gat(emb_w1, x, T1, E1, 20000, 40000, 8, bid - 2048, tid);
  else                 gat(emb_w2, x, T2, E2, 60000, 40000, 6, bid - 2560, tid);
}

// ---------------- 128-tile f16 GEMM body + 3-segment wrapper ----------------
struct Seg128 {
  const _Float16* A; int lda;
  const _Float16* Wm; int ldw;
  _Float16* C; int ldc; int Nvalid;
  u8* Cq; int ldq;
  const int* amap; const int* cmap; const int* cnt;
  int K; int nblk;
};

DEVI void gemm128_body(const Seg128& s, int rb, int cb) {
  int valid = s.cnt ? *s.cnt : NROWS;
  if (rb * 128 >= valid) return;
  __shared__ __attribute__((aligned(16))) _Float16 As[128 * 32];
  __shared__ __attribute__((aligned(16))) _Float16 Ws[128 * 32];
  int tid = threadIdx.x;
  int lane = tid & 63, wid = tid >> 6;
  int wr = wid >> 1, wc = wid & 1;
  int sr = wid * 32 + (lane >> 2);
  int arow0 = rb * 128 + sr, arow1 = arow0 + 16;
  if (s.amap) { arow0 = s.amap[arow0]; arow1 = s.amap[arow1]; }
  int ko = (lane & 3) * 8;
  const _Float16* ag0 = s.A + (size_t)arow0 * s.lda + ko;
  const _Float16* ag1 = s.A + (size_t)arow1 * s.lda + ko;
  const _Float16* wg0 = s.Wm + (size_t)(cb * 128 + sr) * s.ldw + ko;
  const _Float16* wg1 = wg0 + (size_t)16 * s.ldw;
  _Float16* as0 = As + (wid * 32) * 32;
  _Float16* as1 = as0 + 16 * 32;
  _Float16* ws0 = Ws + (wid * 32) * 32;
  _Float16* ws1 = ws0 + 16 * 32;
  f32x4 acc[4][4] = {};
  int lr = lane & 15, lk = (lane >> 4) * 8;
  const int nk = s.K >> 5;
  for (int kt = 0; kt < nk; ++kt) {
    int kofs = kt * 32;
    glds16(ag0 + kofs, as0);
    glds16(ag1 + kofs, as1);
    glds16(wg0 + kofs, ws0);
    glds16(wg1 + kofs, ws1);
    __syncthreads();
    f16x8 af[4], bf[4];
    #pragma unroll
    for (int mi = 0; mi < 4; mi++)
      af[mi] = *(const f16x8*)(As + (wr * 64 + mi * 16 + lr) * 32 + lk);
    #pragma unroll
    for (int ni = 0; ni < 4; ni++)
      bf[ni] = *(const f16x8*)(Ws + (wc * 64 + ni * 16 + lr) * 32 + lk);
    #pragma unroll
    for (int mi = 0; mi < 4; mi++)
      #pragma unroll
      for (int ni = 0; ni < 4; ni++)
        acc[mi][ni] = __builtin_amdgcn_mfma_f32_16x16x32_f16(af[mi], bf[ni], acc[mi][ni], 0, 0, 0);
    __syncthreads();
  }
  #pragma unroll
  for (int mi = 0; mi < 4; mi++) {
    #pragma unroll
    for (int j = 0; j < 4; j++) {
      int rl = wr * 64 + mi * 16 + (lane >> 4) * 4 + j;
      int rg = rb * 128 + rl;
      if (rg >= valid) continue;
      int orow = s.cmap ? s.cmap[rg] : rg;
      #pragma unroll
      for (int ni = 0; ni < 4; ni++) {
        int col = cb * 128 + wc * 64 + ni * 16 + (lane & 15);
        if (col < s.Nvalid) {
          float v = acc[mi][ni][j];
          s.C[(size_t)orow * s.ldc + col] = (_Float16)v;
          if (s.Cq) s.Cq[(size_t)orow * s.ldq + swzb(col, orow)] = (u8)to_e4m3(v * 8.f);
        }
      }
    }
  }
}

__global__ __launch_bounds__(256)
void gemm128_multi(Seg128 s0, Seg128 s1, Seg128 s2) {
  int b = blockIdx.x;
  if (b < s0.nblk)                    { gemm128_body(s0, b & 15, b >> 4); }
  else if (b < s0.nblk + s1.nblk)     { b -= s0.nblk; gemm128_body(s1, b & 15, b >> 4); }
  else                                { b -= s0.nblk + s1.nblk; gemm128_body(s2, b & 15, b >> 4); }
}

// ------- MX-fp8 128x128 GEMM + online-LSE (m148 blueprint, conflict-free b128 reads) -------
struct SegL {
  const u8* A; const u8* W; const float* bias; const int* cnt;
  float* pm; float* ps; int pstride; int K; int nrb; int nblk;
};

__global__ __launch_bounds__(256, 3)
void gemm_lse8_multi(SegL s0, SegL s1, SegL s2)
{
  __shared__ __attribute__((aligned(16))) u8 As[16384];   // 128 rows x 128B
  __shared__ __attribute__((aligned(16))) u8 Ws[16384];

  int b = blockIdx.x;
  SegL s;
  if (b < s0.nblk) s = s0;
  else if (b < s0.nblk + s1.nblk) { s = s1; b -= s0.nblk; }
  else { s = s2; b -= s0.nblk + s1.nblk; }

  int q = s.nblk >> 3;                       // nblk % 8 == 0
  int w = (b & 7) * q + (b >> 3);            // XCD-contiguous cb panels
  int rb = w % s.nrb, cb = w / s.nrb;
  int valid = s.cnt ? *s.cnt : NROWS;
  if (rb * 128 >= valid) return;

  const int K = s.K;
  int tid = threadIdx.x;
  int lane = tid & 63, wid = tid >> 6;
  int wr = wid >> 1, wc = wid & 1;
  int lr = lane & 15, g = lane >> 4;

  // staging: 1024 16B-chunks per matrix, 4 per thread; global pre-swizzled (pure memcpy)
  const u8* aS[4]; const u8* bS[4]; int dL[4];
  #pragma unroll
  for (int i = 0; i < 4; ++i) {
    int c = tid + i * 256;
    int r = c >> 3, j = c & 7;
    aS[i] = s.A + (size_t)(rb * 128 + r) * K + j * 16;
    bS[i] = s.W + (size_t)((size_t)cb * 128 + r) * K + j * 16;
    dL[i] = c * 16;
  }

  // fragment reads: 2x ds_read_b128 per operand; phys16 = (2g+i)^SIG(lr).
  // Per instruction: 8 lanes/16B-slot = 8 lanes per 4-bank group -> conflict-free (LDS peak).
  int sig = SIG(lr);
  int p0 = ((2 * g + 0) ^ sig) << 4;
  int p1 = ((2 * g + 1) ^ sig) << 4;
  int arow = (wr * 64 + lr) * 128;           // + mi*2048
  int brow = (wc * 64 + lr) * 128;           // + ni*2048

  f32x4 acc[4][4] = {};
  const int nk = K >> 7;                     // BK = 128 bytes; nk >= 1

  union UV { i32x8 v; i32x4 h[2]; };
  for (int kt = 0; kt < nk; ++kt) {
    int k0 = kt * 128;
    #pragma unroll
    for (int i = 0; i < 4; ++i) glds16(aS[i] + k0, As + dL[i]);
    #pragma unroll
    for (int i = 0; i < 4; ++i) glds16(bS[i] + k0, Ws + dL[i]);
    __syncthreads();            // compiler drains vmcnt before barrier
    i32x8 bq[4];
    #pragma unroll
    for (int ni = 0; ni < 4; ++ni) {
      UV bv;
      const u8* bp = Ws + brow + ni * 2048;
      bv.h[0] = *(const i32x4*)(bp + p0);
      bv.h[1] = *(const i32x4*)(bp + p1);
      bq[ni] = bv.v;
    }
    #pragma unroll
    for (int mi = 0; mi < 4; ++mi) {
      UV av;
      const u8* ap = As + arow + mi * 2048;
      av.h[0] = *(const i32x4*)(ap + p0);
      av.h[1] = *(const i32x4*)(ap + p1);
      #pragma unroll
      for (int ni = 0; ni < 4; ++ni)
        acc[mi][ni] = __builtin_amdgcn_mfma_scale_f32_16x16x128_f8f6f4(
                        av.v, bq[ni], acc[mi][ni], 0, 0, 0, 127, 0, 127);
    }
    __syncthreads();
  }

  // ---- epilogue: unscale 1/512 + bias, per-row (max,sumexp) over 128 cols ----
  float* lm = (float*)As;                    // [2 wc][128 rows]
  float* lsm = lm + 256;
  float bv4[4];
  #pragma unroll
  for (int ni = 0; ni < 4; ++ni) bv4[ni] = s.bias[cb * 128 + wc * 64 + ni * 16 + lr];
  constexpr float INV = 1.f / 512.f;
  #pragma unroll
  for (int mi = 0; mi < 4; ++mi) {
    #pragma unroll
    for (int j = 0; j < 4; ++j) {
      float v0 = acc[mi][0][j] * INV + bv4[0];
      float v1 = acc[mi][1][j] * INV + bv4[1];
      float v2 = acc[mi][2][j] * INV + bv4[2];
      float v3 = acc[mi][3][j] * INV + bv4[3];
      float m = fmaxf(fmaxf(v0, v1), fmaxf(v2, v3));
      #pragma unroll
      for (int d = 1; d < 16; d <<= 1) m = fmaxf(m, __shfl_xor(m, d));
      float sm = __expf(v0 - m) + __expf(v1 - m) + __expf(v2 - m) + __expf(v3 - m);
      #pragma unroll
      for (int d = 1; d < 16; d <<= 1) sm += __shfl_xor(sm, d);
      if (lr == 0) {
        int row = wr * 64 + mi * 16 + g * 4 + j;
        lm[wc * 128 + row] = m; lsm[wc * 128 + row] = sm;
      }
    }
  }
  __syncthreads();
  if (tid < 128) {
    float m0 = lm[tid], m1 = lm[128 + tid];
    float M = fmaxf(m0, m1);
    float S = lsm[tid] * __expf(m0 - M) + lsm[128 + tid] * __expf(m1 - M);
    int gr = rb * 128 + tid;
    s.pm[(size_t)gr * s.pstride + cb] = M;
    s.ps[(size_t)gr * s.pstride + cb] = S;
  }
}

// ---------------- finish: target logits + LSE reduce + NLL ----------------
DEVI float lsew(const float* m, const float* s, int nb, int lane) {
  float M = -3e38f;
  for (int i = lane; i < nb; i += 64) M = fmaxf(M, m[i]);
  #pragma unroll
  for (int d = 1; d < 64; d <<= 1) M = fmaxf(M, __shfl_xor(M, d));
  float S = 0.f;
  for (int i = lane; i < nb; i += 64) S += s[i] * __expf(m[i] - M);
  #pragma unroll
  for (int d = 1; d < 64; d <<= 1) S += __shfl_xor(S, d);
  return M + __logf(S);
}

__global__ void finish_kernel(const _Float16* __restrict__ ph0, const u8* __restrict__ headw,
                              const float* __restrict__ headb,
                              const _Float16* __restrict__ ph1c, const u8* __restrict__ w1q,
                              const float* __restrict__ b1p,
                              const _Float16* __restrict__ ph2c, const u8* __restrict__ w2q,
                              const float* __restrict__ b2p,
                              const int* __restrict__ headcol, const int* __restrict__ tailpos,
                              const int* __restrict__ pos1, const int* __restrict__ pos2,
                              const int* __restrict__ cl,
                              const float* __restrict__ pmh, const float* __restrict__ psh,
                              const float* __restrict__ pm1, const float* __restrict__ ps1,
                              const float* __restrict__ pm2, const float* __restrict__ ps2,
                              float* __restrict__ out)
{
  int n = blockIdx.x;
  int tid = threadIdx.x, lane = tid & 63, wid = tid >> 6;
  __shared__ float sh[6];
  int c = cl[n];
  constexpr float IW = 1.f / 64.f;
  if (wid == 0) {
    int hc = headcol[n];
    const f16x8* a = (const f16x8*)(ph0 + (size_t)n * 1024 + lane * 16);
    float s = 0.f;
    #pragma unroll
    for (int u = 0; u < 2; u++) {
      unsigned long wq = *(const unsigned long*)(headw + (size_t)hc * 1024 + swzb(lane * 16 + u * 8, hc));
      f16x8 av = a[u];
      #pragma unroll
      for (int j = 0; j < 8; j++) s += (float)av[j] * fr8((unsigned)(wq >> (8 * j)) & 0xFFu);
    }
    #pragma unroll
    for (int d = 1; d < 64; d <<= 1) s += __shfl_xor(s, d);
    if (lane == 0) sh[0] = s * IW + headb[hc];
  } else if (wid == 1 && c == 1) {
    int p = pos1[n], t = tailpos[n];
    f16x4 av = *(const f16x4*)(ph1c + (size_t)p * 256 + lane * 4);
    const u8* ww = w1q + (size_t)t * 256 + swzb(lane * 4, t);
    float s = (float)av[0] * fr8(ww[0]) + (float)av[1] * fr8(ww[1])
            + (float)av[2] * fr8(ww[2]) + (float)av[3] * fr8(ww[3]);
    #pragma unroll
    for (int d = 1; d < 64; d <<= 1) s += __shfl_xor(s, d);
    float l = lsew(pm1 + (size_t)p * PSTT, ps1 + (size_t)p * PSTT, NCBT, lane);
    if (lane == 0) { sh[1] = s * IW + b1p[t]; sh[4] = l; }
  } else if (wid == 2 && c == 2) {
    int p = pos2[n], t = tailpos[n];
    const _Float16* a = ph2c + (size_t)p * 128 + lane * 2;
    const u8* ww = w2q + (size_t)t * 128 + swzb(lane * 2, t);
    float s = (float)a[0] * fr8(ww[0]) + (float)a[1] * fr8(ww[1]);
    #pragma unroll
    for (int d = 1; d < 64; d <<= 1) s += __shfl_xor(s, d);
    float l = lsew(pm2 + (size_t)p * PSTT, ps2 + (size_t)p * PSTT, NCBT, lane);
    if (lane == 0) { sh[2] = s * IW + b2p[t]; sh[5] = l; }
  } else if (wid == 3) {
    float l = lsew(pmh + (size_t)n * PSTH, psh + (size_t)n * PSTH, NCBH, lane);
    if (lane == 0) sh[3] = l;
  }
  __syncthreads();
  if (tid == 0) {
    float nll = sh[3] - sh[0];
    if (c == 1)      nll += sh[4] - sh[1];
    else if (c == 2) nll += sh[5] - sh[2];
    out[n] = nll;
  }
}

// ---------------- driver ----------------
extern "C" void kernel_launch(void* const* d_in, const int* in_sizes, int n_in,
                              void* d_out, int out_size, void* d_ws, size_t ws_size,
                              hipStream_t stream)
{
  const int*   x         = (const int*)d_in[0];
  const int*   labels    = (const int*)d_in[1];
  const float* emb_w0    = (const float*)d_in[2];
  const float* emb_w1    = (const float*)d_in[3];
  const float* emb_w2    = (const float*)d_in[4];
  const float* emb_proj0 = (const float*)d_in[5];
  const float* emb_proj1 = (const float*)d_in[6];
  const float* emb_proj2 = (const float*)d_in[7];
  const float* out_w0    = (const float*)d_in[8];
  const float* out_b0    = (const float*)d_in[9];
  const float* out_w1    = (const float*)d_in[10];
  const float* out_b1    = (const float*)d_in[11];
  const float* out_w2    = (const float*)d_in[12];
  const float* out_b2    = (const float*)d_in[13];
  const float* out_proj0 = (const float*)d_in[14];
  const float* out_proj1 = (const float*)d_in[15];
  const float* out_proj2 = (const float*)d_in[16];
  const float* cluster_w = (const float*)d_in[17];
  const float* cluster_b = (const float*)d_in[18];
  float* out = (float*)d_out;

  char* ws = (char*)d_ws;
  size_t off = 0;
  auto alloc = [&](size_t bytes) -> void* {
    void* p = ws + off;
    off = (off + bytes + 255) & ~(size_t)255;
    return p;
  };
  u8*    headw = (u8*)alloc((size_t)HEADP * 1024);
  float* headb = (float*)alloc((size_t)HEADP * 4);
  u8*    w1q   = (u8*)alloc((size_t)VTP * 256);
  float* b1p   = (float*)alloc((size_t)VTP * 4);
  u8*    w2q   = (u8*)alloc((size_t)VTP * 128);
  float* b2p   = (float*)alloc((size_t)VTP * 4);
  _Float16* ep0f = (_Float16*)alloc((size_t)1024 * 1024 * 2);
  _Float16* ep1f = (_Float16*)alloc((size_t)1024 * 256 * 2);
  _Float16* ep2f = (_Float16*)alloc((size_t)1024 * 64 * 2);
  _Float16* op0T = (_Float16*)alloc((size_t)1024 * 1024 * 2);
  _Float16* op1T = (_Float16*)alloc((size_t)256 * 1024 * 2);
  _Float16* op2T = (_Float16*)alloc((size_t)128 * 1024 * 2);
  _Float16* E0   = (_Float16*)alloc((size_t)NROWS * 1024 * 2);
  _Float16* E1   = (_Float16*)alloc((size_t)NROWS * 256 * 2);
  _Float16* E2   = (_Float16*)alloc((size_t)NROWS * 64 * 2);
  _Float16* hid  = (_Float16*)alloc((size_t)NROWS * 1024 * 2);
  _Float16* ph0  = (_Float16*)alloc((size_t)NROWS * 1024 * 2);
  u8*       ph0q = (u8*)alloc((size_t)NROWS * 1024);
  _Float16* ph1c = (_Float16*)alloc((size_t)NROWS * 256 * 2);
  u8*       ph1q = (u8*)alloc((size_t)NROWS * 256);
  _Float16* ph2c = (_Float16*)alloc((size_t)NROWS * 128 * 2);
  u8*       ph2q = (u8*)alloc((size_t)NROWS * 128);
  float* pmh = (float*)alloc((size_t)NROWS * PSTH * 4);
  float* psh = (float*)alloc((size_t)NROWS * PSTH * 4);
  float* pm1 = (float*)alloc((size_t)NROWS * PSTT * 4);
  float* ps1 = (float*)alloc((size_t)NROWS * PSTT * 4);
  float* pm2 = (float*)alloc((size_t)NROWS * PSTT * 4);
  float* ps2 = (float*)alloc((size_t)NROWS * PSTT * 4);
  int* lists = (int*)alloc(5 * NROWS * 4);
  int* L1 = lists;
  int* L2 = lists + 2048;
  int* T0 = lists + 4096;
  int* T1 = lists + 6144;
  int* T2 = lists + 8192;
  int* counts  = (int*)alloc(16 * 4);
  int* cl      = (int*)alloc(NROWS * 4);
  int* headcol = (int*)alloc(NROWS * 4);
  int* tailpos = (int*)alloc(NROWS * 4);
  int* pos1    = (int*)alloc(NROWS * 4);
  int* pos2    = (int*)alloc(NROWS * 4);
  (void)ws_size; (void)in_sizes; (void)n_in; (void)out_size;

  fused_pack<<<PB_I, 256, 0, stream>>>(out_w0, out_b0, cluster_w, cluster_b,
                                       out_w1, out_b1, out_w2, out_b2,
                                       emb_proj0, emb_proj1, emb_proj2,
                                       out_proj0, out_proj1, out_proj2,
                                       headw, headb, w1q, b1p, w2q, b2p,
                                       ep0f, ep1f, ep2f, op0T, op1T, op2T,
                                       lists, counts);

  prep_par<<<8, 256, 0, stream>>>(x, labels, cl, headcol, tailpos, pos1, pos2,
                                  L1, L2, T0, T1, T2, counts);

  fused_gather<<<2688, 256, 0, stream>>>(emb_w0, emb_w1, emb_w2, x, T0, T1, T2, E0, E1, E2);

  // hidden per token cluster (scatter via T-lists): 3 segments, one launch
  Seg128 h0 = {E0, 1024, ep0f, 1024, hid, 1024, 1024, nullptr, 0, nullptr, T0, counts + 2, 1024, 128};
  Seg128 h1 = {E1, 256,  ep1f, 256,  hid, 1024, 1024, nullptr, 0, nullptr, T1, counts + 3, 256,  128};
  Seg128 h2 = {E2, 64,   ep2f, 64,   hid, 1024, 1024, nullptr, 0, nullptr, T2, counts + 4, 64,   128};
  gemm128_multi<<<384, 256, 0, stream>>>(h0, h1, h2);

  // projections (dual-write f16 + swizzled fp8 x8): 3 segments, one launch
  Seg128 p0 = {hid, 1024, op0T, 1024, ph0,  1024, 1024, ph0q, 1024, nullptr, nullptr, nullptr,   1024, 128};
  Seg128 p1 = {hid, 1024, op1T, 1024, ph1c, 256,  256,  ph1q, 256,  L1,      nullptr, counts + 0, 1024, 32};
  Seg128 p2 = {hid, 1024, op2T, 1024, ph2c, 128,  128,  ph2q, 128,  L2,      nullptr, counts + 1, 1024, 16};
  gemm128_multi<<<176, 256, 0, stream>>>(p0, p1, p2);

  // MX-fp8 logits + online-LSE partials: head + both tails in ONE launch (128x128, BK=128)
  SegL l0 = {ph0q, headw, headb, nullptr,    pmh, psh, PSTH, 1024, 16, 16 * NCBH};
  SegL l1 = {ph1q, w1q,   b1p,   counts + 0, pm1, ps1, PSTT, 256,  8,  8 * NCBT};
  SegL l2 = {ph2q, w2q,   b2p,   counts + 1, pm2, ps2, PSTT, 128,  8,  8 * NCBT};
  gemm_lse8_multi<<<16 * NCBH + 16 * NCBT, 256, 0, stream>>>(l0, l1, l2);

  finish_kernel<<<NROWS, 256, 0, stream>>>(ph0, headw, headb, ph1c, w1q, b1p,
                                           ph2c, w2q, b2p, headcol, tailpos, pos1, pos2, cl,
                                           pmh, psh, pm1, ps1, pm2, ps2, out);
}

// Round 12
// 252.044 us; speedup vs baseline: 1.2492x; 1.0131x over previous
//
#include <hip/hip_runtime.h>

typedef _Float16 f16x8 __attribute__((ext_vector_type(8)));
typedef _Float16 f16x4 __attribute__((ext_vector_type(4)));
typedef float f32x4 __attribute__((ext_vector_type(4)));
typedef int i32x4 __attribute__((ext_vector_type(4)));
typedef int i32x8 __attribute__((ext_vector_type(8)));
typedef unsigned char u8;

#define DEVI __device__ __forceinline__

constexpr int NROWS = 2048;
constexpr int HEADV = 20002;
constexpr int HEADP = 20480;   // 160*128
constexpr int NCBH  = 160;
constexpr int VT    = 40000;
constexpr int VTP   = 40320;   // 315*128
constexpr int NCBT  = 315;

DEVI void glds16(const void* g, void* l) {
  __builtin_amdgcn_global_load_lds((const __attribute__((address_space(1))) unsigned int*)g,
                                   (__attribute__((address_space(3))) unsigned int*)l,
                                   16, 0, 0);
}

// fp8 storage swizzle, 16B granularity within each 128B K-group.
// SIG(r)=r&7: for b128 fragment reads (row=lane&15), 8 consecutive lanes cover all
// 8 16B slots = all 32 banks exactly once -> conflict-free. Involution; staging linear.
#define SIG(r) ((r) & 7)
DEVI int swzb(int b, int r) {
  return (b & ~127) | ((((b >> 4) & 7) ^ SIG(r)) << 4) | (b & 15);
}

// ---------------- fp8 e4m3fn converters (hand-rolled, RNE) ----------------
DEVI unsigned int to_e4m3(float f) {
  unsigned u = __float_as_uint(f);
  unsigned s = (u >> 24) & 0x80u;
  float a = fabsf(f);
  if (!(a < 448.f)) return s | 0x7E;
  if (a < 0.00097656f) return s;
  int exp = (int)((u >> 23) & 0xFF) - 127;
  int qexp = exp < -6 ? -6 : exp;
  int n = __float2int_rn(a * exp2f((float)(3 - qexp)));
  if (n >= 16) { qexp++; n = 8; }
  return s | (unsigned)(n < 8 ? n : (((qexp + 7) << 3) | (n - 8)));
}

DEVI float fr8(unsigned b) {
  unsigned e = (b >> 3) & 15u, m = b & 7u;
  float v;
  if (e) v = __uint_as_float(((e + 120u) << 23) | (m << 20));
  else   v = (float)m * 0.001953125f;
  return (b & 0x80u) ? -v : v;
}

// ---------------- parallel prep (atomic compaction; list order irrelevant) ----------------
__global__ void prep_par(const int* __restrict__ x, const int* __restrict__ labels,
                         int* cl, int* headcol, int* tailpos, int* pos1, int* pos2,
                         int* L1, int* L2, int* T0, int* T1, int* T2, int* counts)
{
  int n = blockIdx.x * 256 + threadIdx.x;
  int l = labels[n];
  int c = l < 20000 ? 0 : (l < 60000 ? 1 : 2);
  cl[n] = c;
  headcol[n] = c == 0 ? l : (c == 1 ? 20001 : 20000);
  tailpos[n] = c == 1 ? l - 20000 : (c == 2 ? l - 60000 : 0);
  if (c == 1) { int s = atomicAdd(&counts[0], 1); pos1[n] = s; L1[s] = n; }
  else if (c == 2) { int s = atomicAdd(&counts[1], 1); pos2[n] = s; L2[s] = n; }
  int t = x[n];
  int tc = t < 20000 ? 0 : (t < 60000 ? 1 : 2);
  int s = atomicAdd(&counts[2 + tc], 1);
  (tc == 0 ? T0 : tc == 1 ? T1 : T2)[s] = n;
}

// ---------------- fused pack / convert / transpose (+ zero lists/counters) ----------------
constexpr int PB_A = HEADP * 1024 / 8 / 256;          // headw fp8 (swizzled)
constexpr int PB_B = PB_A + VTP * 256 / 8 / 256;      // w1q
constexpr int PB_C = PB_B + VTP * 128 / 8 / 256;      // w2q
constexpr int PB_D = PB_C + 1024;                     // ep0f
constexpr int PB_E = PB_D + 256;                      // ep1f
constexpr int PB_F = PB_E + 64;                       // ep2f
constexpr int PB_G = PB_F + 1024;                     // op0T
constexpr int PB_H = PB_G + 256;                      // op1T
constexpr int PB_I = PB_H + 128;                      // op2T

DEVI void cvt_f16(const float* src, _Float16* dst, int vb, int tid) {
  int g = vb * 256 + tid;
  float4 v = *(const float4*)(src + (size_t)g * 4);
  f16x4 o = {(_Float16)v.x, (_Float16)v.y, (_Float16)v.z, (_Float16)v.w};
  *(f16x4*)(dst + (size_t)g * 4) = o;
}

DEVI void tr32(const float* in, _Float16* out, int C, int bx, int by, int tid) {
  __shared__ float tile[32][33];
  int c0 = bx * 32, r0 = by * 32;
  int tx = tid & 31, ty = tid >> 5;
  for (int i = 0; i < 4; i++) {
    int c = c0 + tx; int r = r0 + ty + i * 8;
    tile[ty + i * 8][tx] = (c < C) ? in[(size_t)r * C + c] : 0.f;
  }
  __syncthreads();
  for (int i = 0; i < 4; i++)
    out[(size_t)(c0 + ty + i * 8) * 1024 + r0 + tx] = (_Float16)tile[tx][ty + i * 8];
}

DEVI unsigned long pack8(const float* v) {
  unsigned long p = 0;
  #pragma unroll
  for (int j = 0; j < 8; j++) p |= (unsigned long)to_e4m3(v[j] * 64.f) << (8 * j);
  return p;
}

__global__ void fused_pack(const float* __restrict__ out_w0, const float* __restrict__ out_b0,
                           const float* __restrict__ cluster_w, const float* __restrict__ cluster_b,
                           const float* __restrict__ out_w1, const float* __restrict__ out_b1,
                           const float* __restrict__ out_w2, const float* __restrict__ out_b2,
                           const float* __restrict__ emb_proj0, const float* __restrict__ emb_proj1,
                           const float* __restrict__ emb_proj2,
                           const float* __restrict__ out_proj0, const float* __restrict__ out_proj1,
                           const float* __restrict__ out_proj2,
                           u8* headw, float* headb,
                           u8* w1q, float* b1p, u8* w2q, float* b2p,
                           _Float16* ep0f, _Float16* ep1f, _Float16* ep2f,
                           _Float16* op0T, _Float16* op1T, _Float16* op2T,
                           int* lists, int* counts)
{
  int bid = blockIdx.x, tid = threadIdx.x;
  int zi = bid * 256 + tid;
  if (zi < 5 * 2048) lists[zi] = 0;
  if (bid == 41 && tid < 8) counts[tid] = 0;
  if (bid < PB_A) {
    int g = bid * 256 + tid;
    int r = g >> 7, sl = g & 127;
    float v[8] = {};
    if (r < 20000) {
      *(float4*)v = *(const float4*)(out_w0 + (size_t)r * 1024 + sl * 8);
      *(float4*)(v + 4) = *(const float4*)(out_w0 + (size_t)r * 1024 + sl * 8 + 4);
    } else if (r < 20002) {
      *(float4*)v = *(const float4*)(cluster_w + (size_t)(r - 20000) * 1024 + sl * 8);
      *(float4*)(v + 4) = *(const float4*)(cluster_w + (size_t)(r - 20000) * 1024 + sl * 8 + 4);
    }
    *(unsigned long*)(headw + (size_t)r * 1024 + swzb(sl * 8, r)) = pack8(v);
    if (g < HEADP) headb[g] = g < 20000 ? out_b0[g] : (g < HEADV ? cluster_b[g - 20000] : -1e30f);
  } else if (bid < PB_B) {
    int g = (bid - PB_A) * 256 + tid;
    int r = g >> 5, sl = g & 31;
    float v[8] = {};
    if (r < VT) {
      *(float4*)v = *(const float4*)(out_w1 + (size_t)r * 256 + sl * 8);
      *(float4*)(v + 4) = *(const float4*)(out_w1 + (size_t)r * 256 + sl * 8 + 4);
    }
    *(unsigned long*)(w1q + (size_t)r * 256 + swzb(sl * 8, r)) = pack8(v);
    if (g < VTP) b1p[g] = g < VT ? out_b1[g] : -1e30f;
  } else if (bid < PB_C) {
    int g = (bid - PB_B) * 256 + tid;
    int r = g >> 4, sl = g & 15;
    float v[8] = {};
    if (r < VT && sl < 8) {
      *(float4*)v = *(const float4*)(out_w2 + (size_t)r * 64 + sl * 8);
      *(float4*)(v + 4) = *(const float4*)(out_w2 + (size_t)r * 64 + sl * 8 + 4);
    }
    *(unsigned long*)(w2q + (size_t)r * 128 + swzb(sl * 8, r)) = pack8(v);
    if (g < VTP) b2p[g] = g < VT ? out_b2[g] : -1e30f;
  } else if (bid < PB_D) { cvt_f16(emb_proj0, ep0f, bid - PB_C, tid); }
  else if (bid < PB_E) { cvt_f16(emb_proj1, ep1f, bid - PB_D, tid); }
  else if (bid < PB_F) { cvt_f16(emb_proj2, ep2f, bid - PB_E, tid); }
  else if (bid < PB_G) { int l = bid - PB_F; tr32(out_proj0, op0T, 1024, l & 31, l >> 5, tid); }
  else if (bid < PB_H) { int l = bid - PB_G; tr32(out_proj1, op1T, 256, l & 7, l >> 3, tid); }
  else                 { int l = bid - PB_H; tr32(out_proj2, op2T, 64, l & 3, l >> 2, tid); }
}

// ---------------- fused gather ----------------
DEVI void gat(const float* emb, const int* x, const int* list, _Float16* dst,
              int tbase, int vmax, int log2E, int vb, int tid) {
  int g = vb * 256 + tid;
  int r = g >> (log2E - 2);
  int e4 = (g & ((1 << (log2E - 2)) - 1)) << 2;
  int n = list[r];
  int tl = x[n] - tbase;
  tl = tl < 0 ? 0 : (tl >= vmax ? vmax - 1 : tl);
  float4 v = *(const float4*)(emb + ((size_t)tl << log2E) + e4);
  f16x4 o = {(_Float16)(v.x * 32.f), (_Float16)(v.y * 32.f),
             (_Float16)(v.z * 32.f), (_Float16)(v.w * 32.f)};
  *(f16x4*)(dst + ((size_t)r << log2E) + e4) = o;
}

__global__ void fused_gather(const float* __restrict__ emb_w0, const float* __restrict__ emb_w1,
                             const float* __restrict__ emb_w2, const int* __restrict__ x,
                             const int* __restrict__ T0, const int* __restrict__ T1,
                             const int* __restrict__ T2,
                             _Float16* E0, _Float16* E1, _Float16* E2)
{
  int bid = blockIdx.x, tid = threadIdx.x;
  if (bid < 2048)      gat(emb_w0, x, T0, E0, 0, 20000, 10, bid, tid);
  else if (bid < 2560) gat(emb_w1, x, T1, E1, 20000, 40000, 8, bid - 2048, tid);
  else                 gat(emb_w2, x, T2, E2, 60000, 40000, 6, bid - 2560, tid);
}

// ---------------- 128-tile f16 GEMM body + 3-segment wrapper ----------------
struct Seg128 {
  const _Float16* A; int lda;
  const _Float16* Wm; int ldw;
  _Float16* C; int ldc; int Nvalid;
  u8* Cq; int ldq;
  const int* amap; const int* cmap; const int* cnt;
  int K; int nblk;
};

DEVI void gemm128_body(const Seg128& s, int rb, int cb) {
  int valid = s.cnt ? *s.cnt : NROWS;
  if (rb * 128 >= valid) return;
  __shared__ __attribute__((aligned(16))) _Float16 As[128 * 32];
  __shared__ __attribute__((aligned(16))) _Float16 Ws[128 * 32];
  int tid = threadIdx.x;
  int lane = tid & 63, wid = tid >> 6;
  int wr = wid >> 1, wc = wid & 1;
  int sr = wid * 32 + (lane >> 2);
  int arow0 = rb * 128 + sr, arow1 = arow0 + 16;
  if (s.amap) { arow0 = s.amap[arow0]; arow1 = s.amap[arow1]; }
  int ko = (lane & 3) * 8;
  const _Float16* ag0 = s.A + (size_t)arow0 * s.lda + ko;
  const _Float16* ag1 = s.A + (size_t)arow1 * s.lda + ko;
  const _Float16* wg0 = s.Wm + (size_t)(cb * 128 + sr) * s.ldw + ko;
  const _Float16* wg1 = wg0 + (size_t)16 * s.ldw;
  _Float16* as0 = As + (wid * 32) * 32;
  _Float16* as1 = as0 + 16 * 32;
  _Float16* ws0 = Ws + (wid * 32) * 32;
  _Float16* ws1 = ws0 + 16 * 32;
  f32x4 acc[4][4] = {};
  int lr = lane & 15, lk = (lane >> 4) * 8;
  const int nk = s.K >> 5;
  for (int kt = 0; kt < nk; ++kt) {
    int kofs = kt * 32;
    glds16(ag0 + kofs, as0);
    glds16(ag1 + kofs, as1);
    glds16(wg0 + kofs, ws0);
    glds16(wg1 + kofs, ws1);
    __syncthreads();
    f16x8 af[4], bf[4];
    #pragma unroll
    for (int mi = 0; mi < 4; mi++)
      af[mi] = *(const f16x8*)(As + (wr * 64 + mi * 16 + lr) * 32 + lk);
    #pragma unroll
    for (int ni = 0; ni < 4; ni++)
      bf[ni] = *(const f16x8*)(Ws + (wc * 64 + ni * 16 + lr) * 32 + lk);
    #pragma unroll
    for (int mi = 0; mi < 4; mi++)
      #pragma unroll
      for (int ni = 0; ni < 4; ni++)
        acc[mi][ni] = __builtin_amdgcn_mfma_f32_16x16x32_f16(af[mi], bf[ni], acc[mi][ni], 0, 0, 0);
    __syncthreads();
  }
  #pragma unroll
  for (int mi = 0; mi < 4; mi++) {
    #pragma unroll
    for (int j = 0; j < 4; j++) {
      int rl = wr * 64 + mi * 16 + (lane >> 4) * 4 + j;
      int rg = rb * 128 + rl;
      if (rg >= valid) continue;
      int orow = s.cmap ? s.cmap[rg] : rg;
      #pragma unroll
      for (int ni = 0; ni < 4; ni++) {
        int col = cb * 128 + wc * 64 + ni * 16 + (lane & 15);
        if (col < s.Nvalid) {
          float v = acc[mi][ni][j];
          s.C[(size_t)orow * s.ldc + col] = (_Float16)v;
          if (s.Cq) s.Cq[(size_t)orow * s.ldq + swzb(col, orow)] = (u8)to_e4m3(v * 8.f);
        }
      }
    }
  }
}

__global__ __launch_bounds__(256)
void gemm128_multi(Seg128 s0, Seg128 s1, Seg128 s2) {
  int b = blockIdx.x;
  if (b < s0.nblk)                    { gemm128_body(s0, b & 15, b >> 4); }
  else if (b < s0.nblk + s1.nblk)     { b -= s0.nblk; gemm128_body(s1, b & 15, b >> 4); }
  else                                { b -= s0.nblk + s1.nblk; gemm128_body(s2, b & 15, b >> 4); }
}

// ------- MX-fp8 256x128 GEMM + online-LSE; wave owns 64 rows x full 128 cols -------
struct SegL {
  const u8* A; const u8* W; const float* bias; const int* cnt;
  float* pm; float* ps; int K; int nblk;   // partials column-major: pm[cb*2048 + row]
};

__global__ __launch_bounds__(256, 2)
void gemm_lse8_multi(SegL s0, SegL s1, SegL s2)
{
  __shared__ __attribute__((aligned(16))) u8 As[32768];   // 256 rows x 128B
  __shared__ __attribute__((aligned(16))) u8 Ws[16384];   // 128 rows x 128B

  int b = blockIdx.x;
  SegL s;
  if (b < s0.nblk) s = s0;
  else if (b < s0.nblk + s1.nblk) { s = s1; b -= s0.nblk; }
  else { s = s2; b -= s0.nblk + s1.nblk; }

  int q = s.nblk >> 3;                       // nblk % 8 == 0 (nrb = 8)
  int w = (b & 7) * q + (b >> 3);            // XCD-contiguous: consecutive rb share cb panel
  int rb = w & 7, cb = w >> 3;
  int valid = s.cnt ? *s.cnt : NROWS;
  if (rb * 256 >= valid) return;

  const int K = s.K;
  int tid = threadIdx.x;
  int lane = tid & 63, wid = tid >> 6;
  int lr = lane & 15, g = lane >> 4;

  // staging: linear memcpy (global pre-swizzled); A 8 chunks, B 4 chunks per thread
  const u8* aS[8]; int dA[8];
  #pragma unroll
  for (int i = 0; i < 8; ++i) {
    int c = tid + i * 256;
    aS[i] = s.A + (size_t)(rb * 256 + (c >> 3)) * K + (c & 7) * 16;
    dA[i] = c * 16;
  }
  const u8* bS[4]; int dB[4];
  #pragma unroll
  for (int i = 0; i < 4; ++i) {
    int c = tid + i * 256;
    bS[i] = s.W + (size_t)((size_t)cb * 128 + (c >> 3)) * K + (c & 7) * 16;
    dB[i] = c * 16;
  }

  // fragment reads: 2x ds_read_b128; phys16 = (2g+i)^SIG(lr); 8 lanes cover all 32 banks
  int sig = SIG(lr);
  int p0 = ((2 * g + 0) ^ sig) << 4;
  int p1 = ((2 * g + 1) ^ sig) << 4;
  int arow = (wid * 64 + lr) * 128;          // + mi*2048
  int brow = lr * 128;                       // + ni*2048

  f32x4 acc[4][8] = {};
  const int nk = K >> 7;                     // BK = 128 bytes; nk >= 1

  union UV { i32x8 v; i32x4 h[2]; };
  for (int kt = 0; kt < nk; ++kt) {
    int k0 = kt * 128;
    #pragma unroll
    for (int i = 0; i < 8; ++i) glds16(aS[i] + k0, As + dA[i]);
    #pragma unroll
    for (int i = 0; i < 4; ++i) glds16(bS[i] + k0, Ws + dB[i]);
    __syncthreads();            // compiler drains vmcnt before barrier
    i32x8 bq[8];
    #pragma unroll
    for (int ni = 0; ni < 8; ++ni) {
      UV bv;
      const u8* bp = Ws + brow + ni * 2048;
      bv.h[0] = *(const i32x4*)(bp + p0);
      bv.h[1] = *(const i32x4*)(bp + p1);
      bq[ni] = bv.v;
    }
    #pragma unroll
    for (int mi = 0; mi < 4; ++mi) {
      UV av;
      const u8* ap = As + arow + mi * 2048;
      av.h[0] = *(const i32x4*)(ap + p0);
      av.h[1] = *(const i32x4*)(ap + p1);
      #pragma unroll
      for (int ni = 0; ni < 8; ++ni)
        acc[mi][ni] = __builtin_amdgcn_mfma_scale_f32_16x16x128_f8f6f4(
                        av.v, bq[ni], acc[mi][ni], 0, 0, 0, 127, 0, 127);
    }
    __syncthreads();
  }

  // ---- epilogue: unscale 1/512 + bias; wave owns full rows -> in-wave reduce only;
  //      partials column-major (coalesced, no write amplification)
  float bv8[8];
  #pragma unroll
  for (int ni = 0; ni < 8; ++ni) bv8[ni] = s.bias[cb * 128 + ni * 16 + lr];
  constexpr float INV = 1.f / 512.f;
  #pragma unroll
  for (int mi = 0; mi < 4; ++mi) {
    #pragma unroll
    for (int j = 0; j < 4; ++j) {
      float vv[8]; float m = -3e38f;
      #pragma unroll
      for (int ni = 0; ni < 8; ++ni) {
        vv[ni] = acc[mi][ni][j] * INV + bv8[ni];
        m = fmaxf(m, vv[ni]);
      }
      #pragma unroll
      for (int d = 1; d < 16; d <<= 1) m = fmaxf(m, __shfl_xor(m, d));
      float sm = 0.f;
      #pragma unroll
      for (int ni = 0; ni < 8; ++ni) sm += __expf(vv[ni] - m);
      #pragma unroll
      for (int d = 1; d < 16; d <<= 1) sm += __shfl_xor(sm, d);
      if (lr == 0) {
        int row = rb * 256 + wid * 64 + mi * 16 + g * 4 + j;
        s.pm[(size_t)cb * 2048 + row] = m;
        s.ps[(size_t)cb * 2048 + row] = sm;
      }
    }
  }
}

// ---------------- finish: target logits + LSE reduce + NLL ----------------
// partials column-major: element cb at m[cb*2048]
DEVI float lsew(const float* m, const float* s, int nb, int lane) {
  float M = -3e38f;
  for (int i = lane; i < nb; i += 64) M = fmaxf(M, m[(size_t)i * 2048]);
  #pragma unroll
  for (int d = 1; d < 64; d <<= 1) M = fmaxf(M, __shfl_xor(M, d));
  float S = 0.f;
  for (int i = lane; i < nb; i += 64) S += s[(size_t)i * 2048] * __expf(m[(size_t)i * 2048] - M);
  #pragma unroll
  for (int d = 1; d < 64; d <<= 1) S += __shfl_xor(S, d);
  return M + __logf(S);
}

__global__ void finish_kernel(const _Float16* __restrict__ ph0, const u8* __restrict__ headw,
                              const float* __restrict__ headb,
                              const _Float16* __restrict__ ph1c, const u8* __restrict__ w1q,
                              const float* __restrict__ b1p,
                              const _Float16* __restrict__ ph2c, const u8* __restrict__ w2q,
                              const float* __restrict__ b2p,
                              const int* __restrict__ headcol, const int* __restrict__ tailpos,
                              const int* __restrict__ pos1, const int* __restrict__ pos2,
                              const int* __restrict__ cl,
                              const float* __restrict__ pmh, const float* __restrict__ psh,
                              const float* __restrict__ pm1, const float* __restrict__ ps1,
                              const float* __restrict__ pm2, const float* __restrict__ ps2,
                              float* __restrict__ out)
{
  int n = blockIdx.x;
  int tid = threadIdx.x, lane = tid & 63, wid = tid >> 6;
  __shared__ float sh[6];
  int c = cl[n];
  constexpr float IW = 1.f / 64.f;
  if (wid == 0) {
    int hc = headcol[n];
    const f16x8* a = (const f16x8*)(ph0 + (size_t)n * 1024 + lane * 16);
    float s = 0.f;
    #pragma unroll
    for (int u = 0; u < 2; u++) {
      unsigned long wq = *(const unsigned long*)(headw + (size_t)hc * 1024 + swzb(lane * 16 + u * 8, hc));
      f16x8 av = a[u];
      #pragma unroll
      for (int j = 0; j < 8; j++) s += (float)av[j] * fr8((unsigned)(wq >> (8 * j)) & 0xFFu);
    }
    #pragma unroll
    for (int d = 1; d < 64; d <<= 1) s += __shfl_xor(s, d);
    if (lane == 0) sh[0] = s * IW + headb[hc];
  } else if (wid == 1 && c == 1) {
    int p = pos1[n], t = tailpos[n];
    f16x4 av = *(const f16x4*)(ph1c + (size_t)p * 256 + lane * 4);
    const u8* ww = w1q + (size_t)t * 256 + swzb(lane * 4, t);
    float s = (float)av[0] * fr8(ww[0]) + (float)av[1] * fr8(ww[1])
            + (float)av[2] * fr8(ww[2]) + (float)av[3] * fr8(ww[3]);
    #pragma unroll
    for (int d = 1; d < 64; d <<= 1) s += __shfl_xor(s, d);
    float l = lsew(pm1 + p, ps1 + p, NCBT, lane);
    if (lane == 0) { sh[1] = s * IW + b1p[t]; sh[4] = l; }
  } else if (wid == 2 && c == 2) {
    int p = pos2[n], t = tailpos[n];
    const _Float16* a = ph2c + (size_t)p * 128 + lane * 2;
    const u8* ww = w2q + (size_t)t * 128 + swzb(lane * 2, t);
    float s = (float)a[0] * fr8(ww[0]) + (float)a[1] * fr8(ww[1]);
    #pragma unroll
    for (int d = 1; d < 64; d <<= 1) s += __shfl_xor(s, d);
    float l = lsew(pm2 + p, ps2 + p, NCBT, lane);
    if (lane == 0) { sh[2] = s * IW + b2p[t]; sh[5] = l; }
  } else if (wid == 3) {
    float l = lsew(pmh + n, psh + n, NCBH, lane);
    if (lane == 0) sh[3] = l;
  }
  __syncthreads();
  if (tid == 0) {
    float nll = sh[3] - sh[0];
    if (c == 1)      nll += sh[4] - sh[1];
    else if (c == 2) nll += sh[5] - sh[2];
    out[n] = nll;
  }
}

// ---------------- driver ----------------
extern "C" void kernel_launch(void* const* d_in, const int* in_sizes, int n_in,
                              void* d_out, int out_size, void* d_ws, size_t ws_size,
                              hipStream_t stream)
{
  const int*   x         = (const int*)d_in[0];
  const int*   labels    = (const int*)d_in[1];
  const float* emb_w0    = (const float*)d_in[2];
  const float* emb_w1    = (const float*)d_in[3];
  const float* emb_w2    = (const float*)d_in[4];
  const float* emb_proj0 = (const float*)d_in[5];
  const float* emb_proj1 = (const float*)d_in[6];
  const float* emb_proj2 = (const float*)d_in[7];
  const float* out_w0    = (const float*)d_in[8];
  const float* out_b0    = (const float*)d_in[9];
  const float* out_w1    = (const float*)d_in[10];
  const float* out_b1    = (const float*)d_in[11];
  const float* out_w2    = (const float*)d_in[12];
  const float* out_b2    = (const float*)d_in[13];
  const float* out_proj0 = (const float*)d_in[14];
  const float* out_proj1 = (const float*)d_in[15];
  const float* out_proj2 = (const float*)d_in[16];
  const float* cluster_w = (const float*)d_in[17];
  const float* cluster_b = (const float*)d_in[18];
  float* out = (float*)d_out;

  char* ws = (char*)d_ws;
  size_t off = 0;
  auto alloc = [&](size_t bytes) -> void* {
    void* p = ws + off;
    off = (off + bytes + 255) & ~(size_t)255;
    return p;
  };
  u8*    headw = (u8*)alloc((size_t)HEADP * 1024);
  float* headb = (float*)alloc((size_t)HEADP * 4);
  u8*    w1q   = (u8*)alloc((size_t)VTP * 256);
  float* b1p   = (float*)alloc((size_t)VTP * 4);
  u8*    w2q   = (u8*)alloc((size_t)VTP * 128);
  float* b2p   = (float*)alloc((size_t)VTP * 4);
  _Float16* ep0f = (_Float16*)alloc((size_t)1024 * 1024 * 2);
  _Float16* ep1f = (_Float16*)alloc((size_t)1024 * 256 * 2);
  _Float16* ep2f = (_Float16*)alloc((size_t)1024 * 64 * 2);
  _Float16* op0T = (_Float16*)alloc((size_t)1024 * 1024 * 2);
  _Float16* op1T = (_Float16*)alloc((size_t)256 * 1024 * 2);
  _Float16* op2T = (_Float16*)alloc((size_t)128 * 1024 * 2);
  _Float16* E0   = (_Float16*)alloc((size_t)NROWS * 1024 * 2);
  _Float16* E1   = (_Float16*)alloc((size_t)NROWS * 256 * 2);
  _Float16* E2   = (_Float16*)alloc((size_t)NROWS * 64 * 2);
  _Float16* hid  = (_Float16*)alloc((size_t)NROWS * 1024 * 2);
  _Float16* ph0  = (_Float16*)alloc((size_t)NROWS * 1024 * 2);
  u8*       ph0q = (u8*)alloc((size_t)NROWS * 1024);
  _Float16* ph1c = (_Float16*)alloc((size_t)NROWS * 256 * 2);
  u8*       ph1q = (u8*)alloc((size_t)NROWS * 256);
  _Float16* ph2c = (_Float16*)alloc((size_t)NROWS * 128 * 2);
  u8*       ph2q = (u8*)alloc((size_t)NROWS * 128);
  float* pmh = (float*)alloc((size_t)NCBH * 2048 * 4);
  float* psh = (float*)alloc((size_t)NCBH * 2048 * 4);
  float* pm1 = (float*)alloc((size_t)NCBT * 2048 * 4);
  float* ps1 = (float*)alloc((size_t)NCBT * 2048 * 4);
  float* pm2 = (float*)alloc((size_t)NCBT * 2048 * 4);
  float* ps2 = (float*)alloc((size_t)NCBT * 2048 * 4);
  int* lists = (int*)alloc(5 * NROWS * 4);
  int* L1 = lists;
  int* L2 = lists + 2048;
  int* T0 = lists + 4096;
  int* T1 = lists + 6144;
  int* T2 = lists + 8192;
  int* counts  = (int*)alloc(16 * 4);
  int* cl      = (int*)alloc(NROWS * 4);
  int* headcol = (int*)alloc(NROWS * 4);
  int* tailpos = (int*)alloc(NROWS * 4);
  int* pos1    = (int*)alloc(NROWS * 4);
  int* pos2    = (int*)alloc(NROWS * 4);
  (void)ws_size; (void)in_sizes; (void)n_in; (void)out_size;

  fused_pack<<<PB_I, 256, 0, stream>>>(out_w0, out_b0, cluster_w, cluster_b,
                                       out_w1, out_b1, out_w2, out_b2,
                                       emb_proj0, emb_proj1, emb_proj2,
                                       out_proj0, out_proj1, out_proj2,
                                       headw, headb, w1q, b1p, w2q, b2p,
                                       ep0f, ep1f, ep2f, op0T, op1T, op2T,
                                       lists, counts);

  prep_par<<<8, 256, 0, stream>>>(x, labels, cl, headcol, tailpos, pos1, pos2,
                                  L1, L2, T0, T1, T2, counts);

  fused_gather<<<2688, 256, 0, stream>>>(emb_w0, emb_w1, emb_w2, x, T0, T1, T2, E0, E1, E2);

  // hidden per token cluster (scatter via T-lists): 3 segments, one launch
  Seg128 h0 = {E0, 1024, ep0f, 1024, hid, 1024, 1024, nullptr, 0, nullptr, T0, counts + 2, 1024, 128};
  Seg128 h1 = {E1, 256,  ep1f, 256,  hid, 1024, 1024, nullptr, 0, nullptr, T1, counts + 3, 256,  128};
  Seg128 h2 = {E2, 64,   ep2f, 64,   hid, 1024, 1024, nullptr, 0, nullptr, T2, counts + 4, 64,   128};
  gemm128_multi<<<384, 256, 0, stream>>>(h0, h1, h2);

  // projections (dual-write f16 + swizzled fp8 x8): 3 segments, one launch
  Seg128 p0 = {hid, 1024, op0T, 1024, ph0,  1024, 1024, ph0q, 1024, nullptr, nullptr, nullptr,   1024, 128};
  Seg128 p1 = {hid, 1024, op1T, 1024, ph1c, 256,  256,  ph1q, 256,  L1,      nullptr, counts + 0, 1024, 32};
  Seg128 p2 = {hid, 1024, op2T, 1024, ph2c, 128,  128,  ph2q, 128,  L2,      nullptr, counts + 1, 1024, 16};
  gemm128_multi<<<176, 256, 0, stream>>>(p0, p1, p2);

  // MX-fp8 logits + online-LSE partials: head + both tails in ONE launch (256x128, BK=128)
  SegL l0 = {ph0q, headw, headb, nullptr,    pmh, psh, 1024, 8 * NCBH};
  SegL l1 = {ph1q, w1q,   b1p,   counts + 0, pm1, ps1, 256,  8 * NCBT};
  SegL l2 = {ph2q, w2q,   b2p,   counts + 1, pm2, ps2, 128,  8 * NCBT};
  gemm_lse8_multi<<<8 * NCBH + 16 * NCBT, 256, 0, stream>>>(l0, l1, l2);

  finish_kernel<<<NROWS, 256, 0, stream>>>(ph0, headw, headb, ph1c, w1q, b1p,
                                           ph2c, w2q, b2p, headcol, tailpos, pos1, pos2, cl,
                                           pmh, psh, pm1, ps1, pm2, ps2, out);
}